// Round 8
// baseline (376.779 us; speedup 1.0000x reference)
//
#include <hip/hip_runtime.h>
#include <math.h>

#define SQRT2 1.41421356237309515f

typedef __bf16 bf16x8 __attribute__((ext_vector_type(8)));
typedef float f32x4 __attribute__((ext_vector_type(4)));
typedef unsigned short u16x4 __attribute__((ext_vector_type(4)));
typedef unsigned short u16x8 __attribute__((ext_vector_type(8)));

__device__ __forceinline__ unsigned short f2bf(float f) {
    unsigned u = __builtin_bit_cast(unsigned, f);
    u += 0x7fffu + ((u >> 16) & 1u);
    return (unsigned short)(u >> 16);
}

// ---------------- all styles in one kernel (shapes hardcoded)
__global__ __launch_bounds__(256) void style_all(
    const float* __restrict__ z,
    const float* __restrict__ mw0, const float* __restrict__ mb0,
    const float* __restrict__ mw1, const float* __restrict__ mb1,
    const float* __restrict__ mw2, const float* __restrict__ mb2,
    const float* __restrict__ mw3, const float* __restrict__ mb3,
    const float* __restrict__ mw4, const float* __restrict__ mb4,
    const float* __restrict__ mwf, const float* __restrict__ mbf,
    float* __restrict__ s0, float* __restrict__ s1, float* __restrict__ s2,
    float* __restrict__ s3, float* __restrict__ s4, float* __restrict__ sf) {
    int i = blockIdx.x * 256 + threadIdx.x;
    const float* mw; const float* mb; float* o; int Ci, idx; float mul = 1.f;
    if (i < 4096)       { mw = mw0; mb = mb0; o = s0; Ci = 256; idx = i; }
    else if (i < 6144)  { mw = mw1; mb = mb1; o = s1; Ci = 128; idx = i - 4096; }
    else if (i < 8192)  { mw = mw2; mb = mb2; o = s2; Ci = 128; idx = i - 6144; }
    else if (i < 9216)  { mw = mw3; mb = mb3; o = s3; Ci = 64;  idx = i - 8192; }
    else if (i < 10240) { mw = mw4; mb = mb4; o = s4; Ci = 64;  idx = i - 9216; }
    else if (i < 10752) { mw = mwf; mb = mbf; o = sf; Ci = 32;  idx = i - 10240;
                          mul = 0.1767766952966369f; }  // 1/sqrt(32)
    else return;
    int b = idx / Ci, ci = idx % Ci;
    const float* zp = z + b * 512;
    const float* wp = mw + ci * 512;
    float acc = 0.f;
#pragma unroll 8
    for (int k = 0; k < 512; ++k) acc += zp[k] * wp[k];
    o[idx] = (acc * 0.04419417382415922f + mb[ci]) * mul;
}

// ---------------- all demods: one wave per (b,co), layer decoded by wave id
__global__ __launch_bounds__(256) void demod_all(
    const float* __restrict__ w0, const float* __restrict__ w1,
    const float* __restrict__ w2, const float* __restrict__ w3,
    const float* __restrict__ w4,
    const float* __restrict__ s0, const float* __restrict__ s1,
    const float* __restrict__ s2, const float* __restrict__ s3,
    const float* __restrict__ s4,
    float* __restrict__ d0, float* __restrict__ d1, float* __restrict__ d2,
    float* __restrict__ d3, float* __restrict__ d4) {
    int wid = blockIdx.x * 4 + (threadIdx.x >> 6);
    int lane = threadIdx.x & 63;
    const float* w; const float* s; float* d; int Co, Ci, idx;
    if (wid < 2048)      { w = w0; s = s0; d = d0; Co = 128; Ci = 256; idx = wid; }
    else if (wid < 4096) { w = w1; s = s1; d = d1; Co = 128; Ci = 128; idx = wid - 2048; }
    else if (wid < 5120) { w = w2; s = s2; d = d2; Co = 64;  Ci = 128; idx = wid - 4096; }
    else if (wid < 6144) { w = w3; s = s3; d = d3; Co = 64;  Ci = 64;  idx = wid - 5120; }
    else if (wid < 6656) { w = w4; s = s4; d = d4; Co = 32;  Ci = 64;  idx = wid - 6144; }
    else return;
    int b = idx / Co, co = idx % Co;
    const float* wp = w + (size_t)co * Ci * 9;
    const float* sp = s + b * Ci;
    float acc = 0.f;
    for (int k = lane; k < Ci * 9; k += 64) {
        int ci = k / 9;
        float v = wp[k], sv = sp[ci];
        acc += v * v * sv * sv;
    }
    for (int off = 32; off > 0; off >>= 1) acc += __shfl_down(acc, off);
    if (lane == 0) d[b * Co + co] = rsqrtf(acc / (float)(Ci * 9) + 1e-8f);
}

// ---------------- pack helpers (CoG = 32 for all)
__device__ __forceinline__ void pack_cw_elem(
    const float* __restrict__ w, unsigned short* __restrict__ dst,
    int i, int Ci, int KT, float sInv) {
    int cil = i & 31;
    int r = i >> 5;
    int col = r % 32; r /= 32;
    int t = r % 9; r /= 9;
    int c = r % KT, g = r / KT;
    int co = g * 32 + col, ci = c * 32 + cil;
    dst[i] = f2bf(w[((size_t)co * Ci + ci) * 9 + t] * sInv);
}
__device__ __forceinline__ void pack_fused_elem(
    const float* __restrict__ w, unsigned short* __restrict__ dst,
    int i, int Ci, int KT, float sInv) {
    int cil = i & 31;
    int r = i >> 5;
    int col = r % 32; r /= 32;
    int t = r % 36; r /= 36;
    int c = r % KT, g = r / KT;
    int co = g * 32 + col, ci = c * 32 + cil;
    int p = t / 9, dd = (t % 9) / 3, ee = t % 3;
    int py = p >> 1, px = p & 1;
    const float k1[4] = {1.f, 3.f, 3.f, 1.f};
    const float* wq = w + ((size_t)co * Ci + ci) * 9;
    float acc = 0.f;
#pragma unroll
    for (int rr = 0; rr < 3; ++rr) {
        int ia = 2 * dd + rr - 1 - py;
        if (ia < 0 || ia > 3) continue;
#pragma unroll
        for (int ss = 0; ss < 3; ++ss) {
            int ib = 2 * ee + ss - 1 - px;
            if (ib < 0 || ib > 3) continue;
            acc += wq[rr * 3 + ss] * k1[ia] * k1[ib];
        }
    }
    dst[i] = f2bf(acc * sInv * (1.f / 16.f));
}

// ---------------- all weight packs in one kernel (segment ranges hardcoded)
__global__ __launch_bounds__(256) void pack_all(
    const float* __restrict__ l0w, const float* __restrict__ l1w,
    const float* __restrict__ l2w, const float* __restrict__ l3w,
    const float* __restrict__ l4w, unsigned short* __restrict__ base) {
    const float sInv1152 = 0.02946278254943948f;
    int i = blockIdx.x * 256 + threadIdx.x;
    if (i < 294912)       pack_cw_elem(l0w, base, i, 256, 8, 1.f / 48.f);
    else if (i < 368640)  pack_cw_elem(l2w, base + 294912, i - 294912, 128, 4, sInv1152);
    else if (i < 387072)  pack_cw_elem(l4w, base + 368640, i - 368640, 64, 2, 1.f / 24.f);
    else if (i < 976896)  pack_fused_elem(l1w, base + 387072, i - 387072, 128, 4, sInv1152);
    else if (i < 1124352) pack_fused_elem(l3w, base + 976896, i - 976896, 64, 2, 1.f / 24.f);
}

// ---------------- composite + transpose to channel-last, x sty0 -> bf16
__global__ __launch_bounds__(256) void composite_cl_kernel(
    const float* __restrict__ fg, const float* __restrict__ mask,
    const float* __restrict__ bg, const float* __restrict__ sty0,
    unsigned short* __restrict__ out) {
    __shared__ unsigned short ldsT[32 * 264];
    int blk = blockIdx.x;
    int b = blk >> 5, y = blk & 31;
    int t = threadIdx.x;
    int x = t & 31, cr = t >> 5;
    const float* sb = sty0 + b * 256;
    float m = 1.f - mask[(b << 10) + (y << 5) + x];
    for (int k = 0; k < 32; ++k) {
        int ci = k * 8 + cr;
        size_t idx = ((size_t)(b * 256 + ci) << 10) + (y << 5) + x;
        float v = fg[idx] + m * bg[idx];
        ldsT[x * 264 + ci] = f2bf(v * sb[ci]);
    }
    __syncthreads();
    int xx = t >> 5, cu = t & 31;
#pragma unroll
    for (int ph = 0; ph < 4; ++ph) {
        int px = ph * 8 + xx;
        u16x8 v = *(const u16x8*)&ldsT[px * 264 + cu * 8];
        *(u16x8*)(out + (((size_t)(b * 32 + y) * 32 + px) << 8) + cu * 8) = v;
    }
}

// ---------------- MFMA 3x3 conv, channel-last, NO LDS: B-fragments direct
// from global into a 6-row register window; weights direct from global.
// OUTMODE 0: f32 split-K partial; 1: bf16 epilogue; 3: l4 + fused final 1x1.
template <int OUTMODE>
__global__ __launch_bounds__(256, 3) void conv3x3_cl(
    const unsigned short* __restrict__ X, const unsigned short* __restrict__ W,
    const float* __restrict__ demod, const float* __restrict__ bias,
    const float* __restrict__ nextsty, const float* __restrict__ finw,
    const float* __restrict__ ob, void* __restrict__ outv,
    int Ci, int Co, int S, int TPS, int KCH, int cogN) {
    const int tid = threadIdx.x;
    const int b = blockIdx.z;
    const int ks = blockIdx.y / cogN, cog = blockIdx.y % cogN;
    const int tile = blockIdx.x;
    const int ty0 = (tile / TPS) * 16, tx0 = (tile % TPS) * 16;
    const int KT = Ci >> 5;
    const int wave = tid >> 6, lane = tid & 63, quad = lane >> 4, l16 = lane & 15;

    f32x4 acc[2][4];
#pragma unroll
    for (int mt = 0; mt < 2; ++mt)
#pragma unroll
        for (int nt = 0; nt < 4; ++nt) acc[mt][nt] = (f32x4){0.f, 0.f, 0.f, 0.f};

    const int gyb = ty0 - 1 + wave * 4;
    const int gxb = tx0 - 1 + l16;

    for (int cc = 0; cc < KCH; ++cc) {
        const int cg = ks * KCH + cc;
        const unsigned short* xb = X + (size_t)cg * 32 + quad * 8;
        const unsigned short* wt = W + (((size_t)cog * KT + cg) * 9) * 1024 + l16 * 32 + quad * 8;
#pragma unroll
        for (int ee = 0; ee < 3; ++ee) {
            const int gx = gxb + ee;
            const bool okx = (unsigned)gx < (unsigned)S;
            bf16x8 bfr[6];
#pragma unroll
            for (int rr = 0; rr < 6; ++rr) {
                int gy = gyb + rr;
                u16x8 v = (u16x8){0, 0, 0, 0, 0, 0, 0, 0};
                if (okx && (unsigned)gy < (unsigned)S)
                    v = *(const u16x8*)(xb + ((size_t)(b * S + gy) * S + gx) * Ci);
                bfr[rr] = __builtin_bit_cast(bf16x8, v);
            }
#pragma unroll
            for (int ty = 0; ty < 3; ++ty) {
                const int t = ty * 3 + ee;
                bf16x8 af0 = *(const bf16x8*)(const void*)(wt + t * 1024);
                bf16x8 af1 = *(const bf16x8*)(const void*)(wt + t * 1024 + 512);
#pragma unroll
                for (int nt = 0; nt < 4; ++nt) {
                    acc[0][nt] = __builtin_amdgcn_mfma_f32_16x16x32_bf16(af0, bfr[nt + ty], acc[0][nt], 0, 0, 0);
                    acc[1][nt] = __builtin_amdgcn_mfma_f32_16x16x32_bf16(af1, bfr[nt + ty], acc[1][nt], 0, 0, 0);
                }
            }
        }
    }
    const int col = tx0 + l16;
    if (OUTMODE == 0) {
        float* out = (float*)outv;
        const size_t PS = (size_t)16 * S * S * Co;
#pragma unroll
        for (int mt = 0; mt < 2; ++mt) {
            int co0 = cog * 32 + mt * 16 + quad * 4;
#pragma unroll
            for (int nt = 0; nt < 4; ++nt) {
                int row = ty0 + wave * 4 + nt;
                *(f32x4*)&out[ks * PS + ((size_t)(b * S + row) * S + col) * Co + co0] = acc[mt][nt];
            }
        }
    } else if (OUTMODE == 1) {
#pragma unroll
        for (int mt = 0; mt < 2; ++mt) {
            int co0 = cog * 32 + mt * 16 + quad * 4;
            f32x4 dm = *(const f32x4*)&demod[b * Co + co0];
            f32x4 bi = *(const f32x4*)&bias[co0];
            f32x4 ns = *(const f32x4*)&nextsty[b * Co + co0];
#pragma unroll
            for (int nt = 0; nt < 4; ++nt) {
                int row = ty0 + wave * 4 + nt;
                size_t base = ((size_t)(b * S + row) * S + col) * Co + co0;
                u16x4 st;
#pragma unroll
                for (int r = 0; r < 4; ++r) {
                    float v = acc[mt][nt][r] * dm[r] + bi[r];
                    v = (v > 0.f ? v : 0.2f * v) * SQRT2 * ns[r];
                    st[r] = f2bf(v);
                }
                *(u16x4*)((unsigned short*)outv + base) = st;
            }
        }
    } else {
        // l4 epilogue + fused final 1x1 (Co=32, cog=0)
        f32x4 dm[2], bi[2], ns[2];
        float fw[3][2][4];
#pragma unroll
        for (int mt = 0; mt < 2; ++mt) {
            int c0 = mt * 16 + quad * 4;
            dm[mt] = *(const f32x4*)&demod[b * Co + c0];
            bi[mt] = *(const f32x4*)&bias[c0];
            ns[mt] = *(const f32x4*)&nextsty[b * Co + c0];
#pragma unroll
            for (int c = 0; c < 3; ++c)
#pragma unroll
                for (int r = 0; r < 4; ++r) fw[c][mt][r] = finw[c * 32 + c0 + r];
        }
        float* out = (float*)outv;
        float ob0 = ob[0], ob1 = ob[1], ob2 = ob[2];
#pragma unroll
        for (int nt = 0; nt < 4; ++nt) {
            int row = ty0 + wave * 4 + nt;
            float p0 = 0.f, p1 = 0.f, p2 = 0.f;
#pragma unroll
            for (int mt = 0; mt < 2; ++mt)
#pragma unroll
                for (int r = 0; r < 4; ++r) {
                    float v = acc[mt][nt][r] * dm[mt][r] + bi[mt][r];
                    v = (v > 0.f ? v : 0.2f * v) * SQRT2 * ns[mt][r];
                    p0 += v * fw[0][mt][r];
                    p1 += v * fw[1][mt][r];
                    p2 += v * fw[2][mt][r];
                }
            p0 += __shfl_xor(p0, 16); p0 += __shfl_xor(p0, 32);
            p1 += __shfl_xor(p1, 16); p1 += __shfl_xor(p1, 32);
            p2 += __shfl_xor(p2, 16); p2 += __shfl_xor(p2, 32);
            if (quad == 0) {
                size_t base = (((size_t)b * 3) << 14) + (row << 7) + col;
                out[base] = p0 + ob0;
                out[base + 16384] = p1 + ob1;
                out[base + 32768] = p2 + ob2;
            }
        }
    }
}

// ---------------- combine split-K partials for l0 (+demod+bias+act+sty1) -> bf16
__global__ __launch_bounds__(256) void combine_l0_kernel(
    const float* __restrict__ P, const float* __restrict__ demod,
    const float* __restrict__ bias, const float* __restrict__ sty1,
    unsigned short* __restrict__ out) {
    int i = blockIdx.x * 256 + threadIdx.x;    // [b][y][x][128]
    int co = i & 127;
    int b = i >> 17;
    float v = P[i] + P[i + (1 << 21)];
    v = v * demod[b * 128 + co] + bias[co];
    v = (v > 0.f ? v : 0.2f * v) * SQRT2 * sty1[b * 128 + co];
    out[i] = f2bf(v);
}

// ---------------- FUSED upconv+blur MFMA, channel-last, parity-per-block,
// MT=2, NO LDS (same direct-global structure as conv3x3_cl).
__global__ __launch_bounds__(256, 3) void upblur_cl(
    const unsigned short* __restrict__ X, const unsigned short* __restrict__ EW,
    const float* __restrict__ demod, const float* __restrict__ bias,
    const float* __restrict__ nextsty, unsigned short* __restrict__ out,
    int Ci, int Co, int S, int TPS) {
    const int tid = threadIdx.x;
    const int b = blockIdx.z;
    const int cog = blockIdx.y >> 2, p = blockIdx.y & 3;
    const int tile = blockIdx.x;
    const int ty0 = (tile / TPS) * 16, tx0 = (tile % TPS) * 16;
    const int KT = Ci >> 5;
    const int wave = tid >> 6, lane = tid & 63, quad = lane >> 4, l16 = lane & 15;

    f32x4 acc[2][4];
#pragma unroll
    for (int mt = 0; mt < 2; ++mt)
#pragma unroll
        for (int nt = 0; nt < 4; ++nt) acc[mt][nt] = (f32x4){0.f, 0.f, 0.f, 0.f};

    const int gyb = ty0 - 1 + wave * 4;
    const int gxb = tx0 - 1 + l16;

    for (int cc = 0; cc < KT; ++cc) {
        const unsigned short* xb = X + (size_t)cc * 32 + quad * 8;
        const unsigned short* wt = EW + (((size_t)cog * KT + cc) * 36 + p * 9) * 1024 + l16 * 32 + quad * 8;
#pragma unroll
        for (int ee = 0; ee < 3; ++ee) {
            const int gx = gxb + ee;
            const bool okx = (unsigned)gx < (unsigned)S;
            bf16x8 bfr[6];
#pragma unroll
            for (int rr = 0; rr < 6; ++rr) {
                int gy = gyb + rr;
                u16x8 v = (u16x8){0, 0, 0, 0, 0, 0, 0, 0};
                if (okx && (unsigned)gy < (unsigned)S)
                    v = *(const u16x8*)(xb + ((size_t)(b * S + gy) * S + gx) * Ci);
                bfr[rr] = __builtin_bit_cast(bf16x8, v);
            }
#pragma unroll
            for (int dd = 0; dd < 3; ++dd) {
                const int t = dd * 3 + ee;
                bf16x8 af0 = *(const bf16x8*)(const void*)(wt + t * 1024);
                bf16x8 af1 = *(const bf16x8*)(const void*)(wt + t * 1024 + 512);
#pragma unroll
                for (int nt = 0; nt < 4; ++nt) {
                    acc[0][nt] = __builtin_amdgcn_mfma_f32_16x16x32_bf16(af0, bfr[nt + dd], acc[0][nt], 0, 0, 0);
                    acc[1][nt] = __builtin_amdgcn_mfma_f32_16x16x32_bf16(af1, bfr[nt + dd], acc[1][nt], 0, 0, 0);
                }
            }
        }
    }
    const int S2 = 2 * S;
    const int py = p >> 1, px = p & 1;
    const int Xc = tx0 + l16, ox = 2 * Xc + px;
#pragma unroll
    for (int mt = 0; mt < 2; ++mt) {
        const int co0 = cog * 32 + mt * 16 + quad * 4;
        f32x4 dm = *(const f32x4*)&demod[b * Co + co0];
        f32x4 bi = *(const f32x4*)&bias[co0];
        f32x4 ns = *(const f32x4*)&nextsty[b * Co + co0];
#pragma unroll
        for (int nt = 0; nt < 4; ++nt) {
            int Y = ty0 + wave * 4 + nt, oy = 2 * Y + py;
            u16x4 st;
#pragma unroll
            for (int r = 0; r < 4; ++r) {
                float v = acc[mt][nt][r] * dm[r] + bi[r];
                v = (v > 0.f ? v : 0.2f * v) * SQRT2 * ns[r];
                st[r] = f2bf(v);
            }
            *(u16x4*)(out + ((size_t)(b * S2 + oy) * S2 + ox) * Co + co0) = st;
        }
    }
}

extern "C" void kernel_launch(void* const* d_in, const int* in_sizes, int n_in,
                              void* d_out, int out_size, void* d_ws, size_t ws_size,
                              hipStream_t stream) {
    const float* fg   = (const float*)d_in[0];
    const float* mask = (const float*)d_in[1];
    const float* bg   = (const float*)d_in[2];
    const float* z    = (const float*)d_in[3];
    const float* l0_w = (const float*)d_in[4];
    const float* l0_mw= (const float*)d_in[5];
    const float* l0_mb= (const float*)d_in[6];
    const float* l0_b = (const float*)d_in[7];
    const float* l1_w = (const float*)d_in[8];
    const float* l1_mw= (const float*)d_in[9];
    const float* l1_mb= (const float*)d_in[10];
    const float* l1_b = (const float*)d_in[11];
    const float* l2_w = (const float*)d_in[12];
    const float* l2_mw= (const float*)d_in[13];
    const float* l2_mb= (const float*)d_in[14];
    const float* l2_b = (const float*)d_in[15];
    const float* l3_w = (const float*)d_in[16];
    const float* l3_mw= (const float*)d_in[17];
    const float* l3_mb= (const float*)d_in[18];
    const float* l3_b = (const float*)d_in[19];
    const float* l4_w = (const float*)d_in[20];
    const float* l4_mw= (const float*)d_in[21];
    const float* l4_mb= (const float*)d_in[22];
    const float* l4_b = (const float*)d_in[23];
    const float* fin_w = (const float*)d_in[24];
    const float* fin_mw= (const float*)d_in[25];
    const float* fin_mb= (const float*)d_in[26];
    const float* obias = (const float*)d_in[27];

    float* wsf = (float*)d_ws;
    float* sty0 = wsf + 0;
    float* sty1 = wsf + 4096;
    float* sty2 = wsf + 6144;
    float* sty3 = wsf + 8192;
    float* sty4 = wsf + 9216;
    float* styf = wsf + 10240;   // pre-scaled by 1/sqrt(32)
    float* dm0  = wsf + 10752;
    float* dm1  = wsf + 12800;
    float* dm2  = wsf + 14848;
    float* dm3  = wsf + 15872;
    float* dm4  = wsf + 16896;
    // packed weights: one region, segment offsets match pack_all
    unsigned short* wbase = (unsigned short*)(wsf + 17408);
    unsigned short* wp0 = wbase;            // 294912 sh
    unsigned short* wp2 = wbase + 294912;   // 73728 sh
    unsigned short* wp4 = wbase + 368640;   // 18432 sh
    unsigned short* ew1 = wbase + 387072;   // 589824 sh
    unsigned short* ew3 = wbase + 976896;   // 147456 sh, end 1124352 sh
    // ---- channel-last activations (float offsets), lifetime-audited:
    // X0 [600000, 2697152)    composite bf16 [b][32][32][256]; dead after l0
    // Pb [2697152, 6891456)   l0 split-K f32 [2][b][32][32][128]; dead after combine
    // Y0 [6891456, 7940032)   l0 out bf16 [b][32][32][128]; dead after upblur1
    // Z1 [7940032, 12134336)  l1 out bf16 [b][64][64][128]; dead after l2
    // Y2 = alias X0           l2 out bf16 [b][64][64][64]; dead after upblur3
    // Z3 [12134336, 20522944) l3 out bf16 [b][128][128][64]; dead after l4
    unsigned short* X0  = (unsigned short*)(wsf + 600000);
    float* Pbuf = wsf + 2697152;
    unsigned short* Y0  = (unsigned short*)(wsf + 6891456);
    unsigned short* Z1  = (unsigned short*)(wsf + 7940032);
    unsigned short* Y2  = X0;
    unsigned short* Z3  = (unsigned short*)(wsf + 12134336);

    dim3 blk(256);

    // prep: 3 fused kernels
    style_all<<<42, blk, 0, stream>>>(z, l0_mw, l0_mb, l1_mw, l1_mb, l2_mw, l2_mb,
                                      l3_mw, l3_mb, l4_mw, l4_mb, fin_mw, fin_mb,
                                      sty0, sty1, sty2, sty3, sty4, styf);
    demod_all<<<1664, blk, 0, stream>>>(l0_w, l1_w, l2_w, l3_w, l4_w,
                                        sty0, sty1, sty2, sty3, sty4,
                                        dm0, dm1, dm2, dm3, dm4);
    pack_all<<<4392, blk, 0, stream>>>(l0_w, l1_w, l2_w, l3_w, l4_w, wbase);

    // composite (NCHW -> channel-last, x sty0) -> X0
    composite_cl_kernel<<<512, blk, 0, stream>>>(fg, mask, bg, sty0, X0);

    // l0: conv 256->128 @32, MT=2, split-K=2 -> Pbuf; combine (x sty1) -> Y0
    conv3x3_cl<0><<<dim3(4, 8, 16), blk, 0, stream>>>(X0, wp0, nullptr, nullptr, nullptr, nullptr, nullptr, Pbuf, 256, 128, 32, 2, 4, 4);
    combine_l0_kernel<<<8192, blk, 0, stream>>>(Pbuf, dm0, l0_b, sty1, Y0);

    // l1: fused upconv+blur 128->128, 32->64, parity-split (x sty2) -> Z1
    upblur_cl<<<dim3(4, 16, 16), blk, 0, stream>>>(Y0, ew1, dm1, l1_b, sty2, Z1, 128, 128, 32, 2);

    // l2: conv 128->64 @64, MT=2 (x sty3) -> Y2
    conv3x3_cl<1><<<dim3(16, 2, 16), blk, 0, stream>>>(Z1, wp2, dm2, l2_b, sty3, nullptr, nullptr, Y2, 128, 64, 64, 4, 4, 2);

    // l3: fused upconv+blur 64->64, 64->128, parity-split (x sty4) -> Z3
    upblur_cl<<<dim3(16, 8, 16), blk, 0, stream>>>(Y2, ew3, dm3, l3_b, sty4, Z3, 64, 64, 64, 4);

    // l4: conv 64->32 @128 + fused final 1x1 (x styf/sqrt32) -> d_out
    conv3x3_cl<3><<<dim3(64, 1, 16), blk, 0, stream>>>(Z3, wp4, dm4, l4_b, styf, fin_w, obias, (float*)d_out, 64, 32, 128, 8, 2, 1);
}

// Round 9
// 342.022 us; speedup vs baseline: 1.1016x; 1.1016x over previous
//
#include <hip/hip_runtime.h>
#include <math.h>

#define SQRT2 1.41421356237309515f

typedef __bf16 bf16x8 __attribute__((ext_vector_type(8)));
typedef float f32x4 __attribute__((ext_vector_type(4)));
typedef unsigned short u16x4 __attribute__((ext_vector_type(4)));
typedef unsigned short u16x8 __attribute__((ext_vector_type(8)));

__device__ __forceinline__ unsigned short f2bf(float f) {
    unsigned u = __builtin_bit_cast(unsigned, f);
    u += 0x7fffu + ((u >> 16) & 1u);
    return (unsigned short)(u >> 16);
}

// ---------------- all styles in one kernel (shapes hardcoded)
__global__ __launch_bounds__(256) void style_all(
    const float* __restrict__ z,
    const float* __restrict__ mw0, const float* __restrict__ mb0,
    const float* __restrict__ mw1, const float* __restrict__ mb1,
    const float* __restrict__ mw2, const float* __restrict__ mb2,
    const float* __restrict__ mw3, const float* __restrict__ mb3,
    const float* __restrict__ mw4, const float* __restrict__ mb4,
    const float* __restrict__ mwf, const float* __restrict__ mbf,
    float* __restrict__ s0, float* __restrict__ s1, float* __restrict__ s2,
    float* __restrict__ s3, float* __restrict__ s4, float* __restrict__ sf) {
    int i = blockIdx.x * 256 + threadIdx.x;
    const float* mw; const float* mb; float* o; int Ci, idx; float mul = 1.f;
    if (i < 4096)       { mw = mw0; mb = mb0; o = s0; Ci = 256; idx = i; }
    else if (i < 6144)  { mw = mw1; mb = mb1; o = s1; Ci = 128; idx = i - 4096; }
    else if (i < 8192)  { mw = mw2; mb = mb2; o = s2; Ci = 128; idx = i - 6144; }
    else if (i < 9216)  { mw = mw3; mb = mb3; o = s3; Ci = 64;  idx = i - 8192; }
    else if (i < 10240) { mw = mw4; mb = mb4; o = s4; Ci = 64;  idx = i - 9216; }
    else if (i < 10752) { mw = mwf; mb = mbf; o = sf; Ci = 32;  idx = i - 10240;
                          mul = 0.1767766952966369f; }  // 1/sqrt(32)
    else return;
    int b = idx / Ci, ci = idx % Ci;
    const float* zp = z + b * 512;
    const float* wp = mw + ci * 512;
    float acc = 0.f;
#pragma unroll 8
    for (int k = 0; k < 512; ++k) acc += zp[k] * wp[k];
    o[idx] = (acc * 0.04419417382415922f + mb[ci]) * mul;
}

// ---------------- all demods: one wave per (b,co), layer decoded by wave id
__global__ __launch_bounds__(256) void demod_all(
    const float* __restrict__ w0, const float* __restrict__ w1,
    const float* __restrict__ w2, const float* __restrict__ w3,
    const float* __restrict__ w4,
    const float* __restrict__ s0, const float* __restrict__ s1,
    const float* __restrict__ s2, const float* __restrict__ s3,
    const float* __restrict__ s4,
    float* __restrict__ d0, float* __restrict__ d1, float* __restrict__ d2,
    float* __restrict__ d3, float* __restrict__ d4) {
    int wid = blockIdx.x * 4 + (threadIdx.x >> 6);
    int lane = threadIdx.x & 63;
    const float* w; const float* s; float* d; int Co, Ci, idx;
    if (wid < 2048)      { w = w0; s = s0; d = d0; Co = 128; Ci = 256; idx = wid; }
    else if (wid < 4096) { w = w1; s = s1; d = d1; Co = 128; Ci = 128; idx = wid - 2048; }
    else if (wid < 5120) { w = w2; s = s2; d = d2; Co = 64;  Ci = 128; idx = wid - 4096; }
    else if (wid < 6144) { w = w3; s = s3; d = d3; Co = 64;  Ci = 64;  idx = wid - 5120; }
    else if (wid < 6656) { w = w4; s = s4; d = d4; Co = 32;  Ci = 64;  idx = wid - 6144; }
    else return;
    int b = idx / Co, co = idx % Co;
    const float* wp = w + (size_t)co * Ci * 9;
    const float* sp = s + b * Ci;
    float acc = 0.f;
    for (int k = lane; k < Ci * 9; k += 64) {
        int ci = k / 9;
        float v = wp[k], sv = sp[ci];
        acc += v * v * sv * sv;
    }
    for (int off = 32; off > 0; off >>= 1) acc += __shfl_down(acc, off);
    if (lane == 0) d[b * Co + co] = rsqrtf(acc / (float)(Ci * 9) + 1e-8f);
}

// ---------------- pack helpers (CoG = 32 for all)
__device__ __forceinline__ void pack_cw_elem(
    const float* __restrict__ w, unsigned short* __restrict__ dst,
    int i, int Ci, int KT, float sInv) {
    int cil = i & 31;
    int r = i >> 5;
    int col = r % 32; r /= 32;
    int t = r % 9; r /= 9;
    int c = r % KT, g = r / KT;
    int co = g * 32 + col, ci = c * 32 + cil;
    dst[i] = f2bf(w[((size_t)co * Ci + ci) * 9 + t] * sInv);
}
__device__ __forceinline__ void pack_fused_elem(
    const float* __restrict__ w, unsigned short* __restrict__ dst,
    int i, int Ci, int KT, float sInv) {
    int cil = i & 31;
    int r = i >> 5;
    int col = r % 32; r /= 32;
    int t = r % 36; r /= 36;
    int c = r % KT, g = r / KT;
    int co = g * 32 + col, ci = c * 32 + cil;
    int p = t / 9, dd = (t % 9) / 3, ee = t % 3;
    int py = p >> 1, px = p & 1;
    const float k1[4] = {1.f, 3.f, 3.f, 1.f};
    const float* wq = w + ((size_t)co * Ci + ci) * 9;
    float acc = 0.f;
#pragma unroll
    for (int rr = 0; rr < 3; ++rr) {
        int ia = 2 * dd + rr - 1 - py;
        if (ia < 0 || ia > 3) continue;
#pragma unroll
        for (int ss = 0; ss < 3; ++ss) {
            int ib = 2 * ee + ss - 1 - px;
            if (ib < 0 || ib > 3) continue;
            acc += wq[rr * 3 + ss] * k1[ia] * k1[ib];
        }
    }
    dst[i] = f2bf(acc * sInv * (1.f / 16.f));
}

// ---------------- all weight packs in one kernel (segment ranges hardcoded)
__global__ __launch_bounds__(256) void pack_all(
    const float* __restrict__ l0w, const float* __restrict__ l1w,
    const float* __restrict__ l2w, const float* __restrict__ l3w,
    const float* __restrict__ l4w, unsigned short* __restrict__ base) {
    const float sInv1152 = 0.02946278254943948f;
    int i = blockIdx.x * 256 + threadIdx.x;
    if (i < 294912)       pack_cw_elem(l0w, base, i, 256, 8, 1.f / 48.f);
    else if (i < 368640)  pack_cw_elem(l2w, base + 294912, i - 294912, 128, 4, sInv1152);
    else if (i < 387072)  pack_cw_elem(l4w, base + 368640, i - 368640, 64, 2, 1.f / 24.f);
    else if (i < 976896)  pack_fused_elem(l1w, base + 387072, i - 387072, 128, 4, sInv1152);
    else if (i < 1124352) pack_fused_elem(l3w, base + 976896, i - 976896, 64, 2, 1.f / 24.f);
}

// ---------------- composite + transpose to channel-last, x sty0 -> bf16
__global__ __launch_bounds__(256) void composite_cl_kernel(
    const float* __restrict__ fg, const float* __restrict__ mask,
    const float* __restrict__ bg, const float* __restrict__ sty0,
    unsigned short* __restrict__ out) {
    __shared__ unsigned short ldsT[32 * 264];
    int blk = blockIdx.x;
    int b = blk >> 5, y = blk & 31;
    int t = threadIdx.x;
    int x = t & 31, cr = t >> 5;
    const float* sb = sty0 + b * 256;
    float m = 1.f - mask[(b << 10) + (y << 5) + x];
    for (int k = 0; k < 32; ++k) {
        int ci = k * 8 + cr;
        size_t idx = ((size_t)(b * 256 + ci) << 10) + (y << 5) + x;
        float v = fg[idx] + m * bg[idx];
        ldsT[x * 264 + ci] = f2bf(v * sb[ci]);
    }
    __syncthreads();
    int xx = t >> 5, cu = t & 31;
#pragma unroll
    for (int ph = 0; ph < 4; ++ph) {
        int px = ph * 8 + xx;
        u16x8 v = *(const u16x8*)&ldsT[px * 264 + cu * 8];
        *(u16x8*)(out + (((size_t)(b * 32 + y) * 32 + px) << 8) + cu * 8) = v;
    }
}

// ---------------- MFMA 3x3 conv, channel-last, LDS-staged (coalesced) with
// hoisted 6x3 register B-window: 18 ds_read_b128 -> 72 MFMA per chunk/wave.
// OUTMODE 0: f32 split-K partial; 1: bf16 epilogue; 3: l4 + fused final 1x1.
template <int OUTMODE>
__global__ __launch_bounds__(256, 3) void conv3x3_cl(
    const unsigned short* __restrict__ X, const unsigned short* __restrict__ W,
    const float* __restrict__ demod, const float* __restrict__ bias,
    const float* __restrict__ nextsty, const float* __restrict__ finw,
    const float* __restrict__ ob, void* __restrict__ outv,
    int Ci, int Co, int S, int TPS, int KCH, int cogN) {
    __shared__ unsigned short ldsX[324 * 36];   // pad 36: conflict-free stride
    const int tid = threadIdx.x;
    const int b = blockIdx.z;
    const int ks = blockIdx.y / cogN, cog = blockIdx.y % cogN;
    const int tile = blockIdx.x;
    const int ty0 = (tile / TPS) * 16, tx0 = (tile % TPS) * 16;
    const int KT = Ci >> 5;
    const int wave = tid >> 6, lane = tid & 63, quad = lane >> 4, l16 = lane & 15;

    f32x4 acc[2][4];
#pragma unroll
    for (int mt = 0; mt < 2; ++mt)
#pragma unroll
        for (int nt = 0; nt < 4; ++nt) acc[mt][nt] = (f32x4){0.f, 0.f, 0.f, 0.f};

    for (int cc = 0; cc < KCH; ++cc) {
        const int cg = ks * KCH + cc;
        const int ci0 = cg * 32;
        for (int u = tid; u < 1296; u += 256) {
            int sp = u >> 2, cq = u & 3;
            int y = sp / 18, xx = sp - y * 18;
            int gy = ty0 - 1 + y, gx = tx0 - 1 + xx;
            u16x8 pk = (u16x8){0, 0, 0, 0, 0, 0, 0, 0};
            if ((unsigned)gy < (unsigned)S && (unsigned)gx < (unsigned)S)
                pk = *(const u16x8*)(X + ((size_t)(b * S + gy) * S + gx) * Ci + ci0 + cq * 8);
            *(u16x8*)&ldsX[sp * 36 + cq * 8] = pk;
        }
        __syncthreads();
        // hoisted register window: rows wave*4+{0..5}, cols l16+{0..2}
        bf16x8 win[6][3];
#pragma unroll
        for (int rr = 0; rr < 6; ++rr)
#pragma unroll
            for (int tx = 0; tx < 3; ++tx)
                win[rr][tx] = *(const bf16x8*)(const void*)&ldsX[((wave * 4 + rr) * 18 + l16 + tx) * 36 + quad * 8];
        const unsigned short* wt = W + (((size_t)cog * KT + cg) * 9) * 1024 + l16 * 32 + quad * 8;
#pragma unroll
        for (int ty = 0; ty < 3; ++ty)
#pragma unroll
            for (int tx = 0; tx < 3; ++tx) {
                const int t = ty * 3 + tx;
                bf16x8 af0 = *(const bf16x8*)(const void*)(wt + t * 1024);
                bf16x8 af1 = *(const bf16x8*)(const void*)(wt + t * 1024 + 512);
#pragma unroll
                for (int nt = 0; nt < 4; ++nt) {
                    acc[0][nt] = __builtin_amdgcn_mfma_f32_16x16x32_bf16(af0, win[nt + ty][tx], acc[0][nt], 0, 0, 0);
                    acc[1][nt] = __builtin_amdgcn_mfma_f32_16x16x32_bf16(af1, win[nt + ty][tx], acc[1][nt], 0, 0, 0);
                }
            }
        __syncthreads();
    }
    const int col = tx0 + l16;
    if (OUTMODE == 0) {
        float* out = (float*)outv;
        const size_t PS = (size_t)16 * S * S * Co;
#pragma unroll
        for (int mt = 0; mt < 2; ++mt) {
            int co0 = cog * 32 + mt * 16 + quad * 4;
#pragma unroll
            for (int nt = 0; nt < 4; ++nt) {
                int row = ty0 + wave * 4 + nt;
                *(f32x4*)&out[ks * PS + ((size_t)(b * S + row) * S + col) * Co + co0] = acc[mt][nt];
            }
        }
    } else if (OUTMODE == 1) {
#pragma unroll
        for (int mt = 0; mt < 2; ++mt) {
            int co0 = cog * 32 + mt * 16 + quad * 4;
            f32x4 dm = *(const f32x4*)&demod[b * Co + co0];
            f32x4 bi = *(const f32x4*)&bias[co0];
            f32x4 ns = *(const f32x4*)&nextsty[b * Co + co0];
#pragma unroll
            for (int nt = 0; nt < 4; ++nt) {
                int row = ty0 + wave * 4 + nt;
                size_t base = ((size_t)(b * S + row) * S + col) * Co + co0;
                u16x4 st;
#pragma unroll
                for (int r = 0; r < 4; ++r) {
                    float v = acc[mt][nt][r] * dm[r] + bi[r];
                    v = (v > 0.f ? v : 0.2f * v) * SQRT2 * ns[r];
                    st[r] = f2bf(v);
                }
                *(u16x4*)((unsigned short*)outv + base) = st;
            }
        }
    } else {
        // l4 epilogue + fused final 1x1 (Co=32, cog=0)
        f32x4 dm[2], bi[2], ns[2];
        float fw[3][2][4];
#pragma unroll
        for (int mt = 0; mt < 2; ++mt) {
            int c0 = mt * 16 + quad * 4;
            dm[mt] = *(const f32x4*)&demod[b * Co + c0];
            bi[mt] = *(const f32x4*)&bias[c0];
            ns[mt] = *(const f32x4*)&nextsty[b * Co + c0];
#pragma unroll
            for (int c = 0; c < 3; ++c)
#pragma unroll
                for (int r = 0; r < 4; ++r) fw[c][mt][r] = finw[c * 32 + c0 + r];
        }
        float* out = (float*)outv;
        float ob0 = ob[0], ob1 = ob[1], ob2 = ob[2];
#pragma unroll
        for (int nt = 0; nt < 4; ++nt) {
            int row = ty0 + wave * 4 + nt;
            float p0 = 0.f, p1 = 0.f, p2 = 0.f;
#pragma unroll
            for (int mt = 0; mt < 2; ++mt)
#pragma unroll
                for (int r = 0; r < 4; ++r) {
                    float v = acc[mt][nt][r] * dm[mt][r] + bi[mt][r];
                    v = (v > 0.f ? v : 0.2f * v) * SQRT2 * ns[mt][r];
                    p0 += v * fw[0][mt][r];
                    p1 += v * fw[1][mt][r];
                    p2 += v * fw[2][mt][r];
                }
            p0 += __shfl_xor(p0, 16); p0 += __shfl_xor(p0, 32);
            p1 += __shfl_xor(p1, 16); p1 += __shfl_xor(p1, 32);
            p2 += __shfl_xor(p2, 16); p2 += __shfl_xor(p2, 32);
            if (quad == 0) {
                size_t base = (((size_t)b * 3) << 14) + (row << 7) + col;
                out[base] = p0 + ob0;
                out[base + 16384] = p1 + ob1;
                out[base + 32768] = p2 + ob2;
            }
        }
    }
}

// ---------------- combine split-K partials for l0 (+demod+bias+act+sty1) -> bf16
__global__ __launch_bounds__(256) void combine_l0_kernel(
    const float* __restrict__ P, const float* __restrict__ demod,
    const float* __restrict__ bias, const float* __restrict__ sty1,
    unsigned short* __restrict__ out) {
    int i = blockIdx.x * 256 + threadIdx.x;    // [b][y][x][128]
    int co = i & 127;
    int b = i >> 17;
    float v = P[i] + P[i + (1 << 21)];
    v = v * demod[b * 128 + co] + bias[co];
    v = (v > 0.f ? v : 0.2f * v) * SQRT2 * sty1[b * 128 + co];
    out[i] = f2bf(v);
}

// ---------------- FUSED upconv+blur MFMA, channel-last, parity-per-block,
// MT=2, LDS-staged with hoisted 6x3 register window.
__global__ __launch_bounds__(256, 3) void upblur_cl(
    const unsigned short* __restrict__ X, const unsigned short* __restrict__ EW,
    const float* __restrict__ demod, const float* __restrict__ bias,
    const float* __restrict__ nextsty, unsigned short* __restrict__ out,
    int Ci, int Co, int S, int TPS) {
    __shared__ unsigned short ldsX[324 * 36];
    const int tid = threadIdx.x;
    const int b = blockIdx.z;
    const int cog = blockIdx.y >> 2, p = blockIdx.y & 3;
    const int tile = blockIdx.x;
    const int ty0 = (tile / TPS) * 16, tx0 = (tile % TPS) * 16;
    const int KT = Ci >> 5;
    const int wave = tid >> 6, lane = tid & 63, quad = lane >> 4, l16 = lane & 15;

    f32x4 acc[2][4];
#pragma unroll
    for (int mt = 0; mt < 2; ++mt)
#pragma unroll
        for (int nt = 0; nt < 4; ++nt) acc[mt][nt] = (f32x4){0.f, 0.f, 0.f, 0.f};

    for (int cc = 0; cc < KT; ++cc) {
        const int ci0 = cc * 32;
        for (int u = tid; u < 1296; u += 256) {
            int sp = u >> 2, cq = u & 3;
            int y = sp / 18, xx = sp - y * 18;
            int gy = ty0 - 1 + y, gx = tx0 - 1 + xx;
            u16x8 pk = (u16x8){0, 0, 0, 0, 0, 0, 0, 0};
            if ((unsigned)gy < (unsigned)S && (unsigned)gx < (unsigned)S)
                pk = *(const u16x8*)(X + ((size_t)(b * S + gy) * S + gx) * Ci + ci0 + cq * 8);
            *(u16x8*)&ldsX[sp * 36 + cq * 8] = pk;
        }
        __syncthreads();
        bf16x8 win[6][3];
#pragma unroll
        for (int rr = 0; rr < 6; ++rr)
#pragma unroll
            for (int ee = 0; ee < 3; ++ee)
                win[rr][ee] = *(const bf16x8*)(const void*)&ldsX[((wave * 4 + rr) * 18 + l16 + ee) * 36 + quad * 8];
        const unsigned short* wt = EW + (((size_t)cog * KT + cc) * 36 + p * 9) * 1024 + l16 * 32 + quad * 8;
#pragma unroll
        for (int dd = 0; dd < 3; ++dd)
#pragma unroll
            for (int ee = 0; ee < 3; ++ee) {
                const int t = dd * 3 + ee;
                bf16x8 af0 = *(const bf16x8*)(const void*)(wt + t * 1024);
                bf16x8 af1 = *(const bf16x8*)(const void*)(wt + t * 1024 + 512);
#pragma unroll
                for (int nt = 0; nt < 4; ++nt) {
                    acc[0][nt] = __builtin_amdgcn_mfma_f32_16x16x32_bf16(af0, win[nt + dd][ee], acc[0][nt], 0, 0, 0);
                    acc[1][nt] = __builtin_amdgcn_mfma_f32_16x16x32_bf16(af1, win[nt + dd][ee], acc[1][nt], 0, 0, 0);
                }
            }
        __syncthreads();
    }
    const int S2 = 2 * S;
    const int py = p >> 1, px = p & 1;
    const int Xc = tx0 + l16, ox = 2 * Xc + px;
#pragma unroll
    for (int mt = 0; mt < 2; ++mt) {
        const int co0 = cog * 32 + mt * 16 + quad * 4;
        f32x4 dm = *(const f32x4*)&demod[b * Co + co0];
        f32x4 bi = *(const f32x4*)&bias[co0];
        f32x4 ns = *(const f32x4*)&nextsty[b * Co + co0];
#pragma unroll
        for (int nt = 0; nt < 4; ++nt) {
            int Y = ty0 + wave * 4 + nt, oy = 2 * Y + py;
            u16x4 st;
#pragma unroll
            for (int r = 0; r < 4; ++r) {
                float v = acc[mt][nt][r] * dm[r] + bi[r];
                v = (v > 0.f ? v : 0.2f * v) * SQRT2 * ns[r];
                st[r] = f2bf(v);
            }
            *(u16x4*)(out + ((size_t)(b * S2 + oy) * S2 + ox) * Co + co0) = st;
        }
    }
}

extern "C" void kernel_launch(void* const* d_in, const int* in_sizes, int n_in,
                              void* d_out, int out_size, void* d_ws, size_t ws_size,
                              hipStream_t stream) {
    const float* fg   = (const float*)d_in[0];
    const float* mask = (const float*)d_in[1];
    const float* bg   = (const float*)d_in[2];
    const float* z    = (const float*)d_in[3];
    const float* l0_w = (const float*)d_in[4];
    const float* l0_mw= (const float*)d_in[5];
    const float* l0_mb= (const float*)d_in[6];
    const float* l0_b = (const float*)d_in[7];
    const float* l1_w = (const float*)d_in[8];
    const float* l1_mw= (const float*)d_in[9];
    const float* l1_mb= (const float*)d_in[10];
    const float* l1_b = (const float*)d_in[11];
    const float* l2_w = (const float*)d_in[12];
    const float* l2_mw= (const float*)d_in[13];
    const float* l2_mb= (const float*)d_in[14];
    const float* l2_b = (const float*)d_in[15];
    const float* l3_w = (const float*)d_in[16];
    const float* l3_mw= (const float*)d_in[17];
    const float* l3_mb= (const float*)d_in[18];
    const float* l3_b = (const float*)d_in[19];
    const float* l4_w = (const float*)d_in[20];
    const float* l4_mw= (const float*)d_in[21];
    const float* l4_mb= (const float*)d_in[22];
    const float* l4_b = (const float*)d_in[23];
    const float* fin_w = (const float*)d_in[24];
    const float* fin_mw= (const float*)d_in[25];
    const float* fin_mb= (const float*)d_in[26];
    const float* obias = (const float*)d_in[27];

    float* wsf = (float*)d_ws;
    float* sty0 = wsf + 0;
    float* sty1 = wsf + 4096;
    float* sty2 = wsf + 6144;
    float* sty3 = wsf + 8192;
    float* sty4 = wsf + 9216;
    float* styf = wsf + 10240;   // pre-scaled by 1/sqrt(32)
    float* dm0  = wsf + 10752;
    float* dm1  = wsf + 12800;
    float* dm2  = wsf + 14848;
    float* dm3  = wsf + 15872;
    float* dm4  = wsf + 16896;
    // packed weights: one region, segment offsets match pack_all
    unsigned short* wbase = (unsigned short*)(wsf + 17408);
    unsigned short* wp0 = wbase;            // 294912 sh
    unsigned short* wp2 = wbase + 294912;   // 73728 sh
    unsigned short* wp4 = wbase + 368640;   // 18432 sh
    unsigned short* ew1 = wbase + 387072;   // 589824 sh
    unsigned short* ew3 = wbase + 976896;   // 147456 sh, end 1124352 sh
    // ---- channel-last activations (float offsets), lifetime-audited:
    // X0 [600000, 2697152)    composite bf16 [b][32][32][256]; dead after l0
    // Pb [2697152, 6891456)   l0 split-K f32 [2][b][32][32][128]; dead after combine
    // Y0 [6891456, 7940032)   l0 out bf16 [b][32][32][128]; dead after upblur1
    // Z1 [7940032, 12134336)  l1 out bf16 [b][64][64][128]; dead after l2
    // Y2 = alias X0           l2 out bf16 [b][64][64][64]; dead after upblur3
    // Z3 [12134336, 20522944) l3 out bf16 [b][128][128][64]; dead after l4
    unsigned short* X0  = (unsigned short*)(wsf + 600000);
    float* Pbuf = wsf + 2697152;
    unsigned short* Y0  = (unsigned short*)(wsf + 6891456);
    unsigned short* Z1  = (unsigned short*)(wsf + 7940032);
    unsigned short* Y2  = X0;
    unsigned short* Z3  = (unsigned short*)(wsf + 12134336);

    dim3 blk(256);

    // prep: 3 fused kernels
    style_all<<<42, blk, 0, stream>>>(z, l0_mw, l0_mb, l1_mw, l1_mb, l2_mw, l2_mb,
                                      l3_mw, l3_mb, l4_mw, l4_mb, fin_mw, fin_mb,
                                      sty0, sty1, sty2, sty3, sty4, styf);
    demod_all<<<1664, blk, 0, stream>>>(l0_w, l1_w, l2_w, l3_w, l4_w,
                                        sty0, sty1, sty2, sty3, sty4,
                                        dm0, dm1, dm2, dm3, dm4);
    pack_all<<<4392, blk, 0, stream>>>(l0_w, l1_w, l2_w, l3_w, l4_w, wbase);

    // composite (NCHW -> channel-last, x sty0) -> X0
    composite_cl_kernel<<<512, blk, 0, stream>>>(fg, mask, bg, sty0, X0);

    // l0: conv 256->128 @32, MT=2, split-K=2 -> Pbuf; combine (x sty1) -> Y0
    conv3x3_cl<0><<<dim3(4, 8, 16), blk, 0, stream>>>(X0, wp0, nullptr, nullptr, nullptr, nullptr, nullptr, Pbuf, 256, 128, 32, 2, 4, 4);
    combine_l0_kernel<<<8192, blk, 0, stream>>>(Pbuf, dm0, l0_b, sty1, Y0);

    // l1: fused upconv+blur 128->128, 32->64, parity-split (x sty2) -> Z1
    upblur_cl<<<dim3(4, 16, 16), blk, 0, stream>>>(Y0, ew1, dm1, l1_b, sty2, Z1, 128, 128, 32, 2);

    // l2: conv 128->64 @64, MT=2 (x sty3) -> Y2
    conv3x3_cl<1><<<dim3(16, 2, 16), blk, 0, stream>>>(Z1, wp2, dm2, l2_b, sty3, nullptr, nullptr, Y2, 128, 64, 64, 4, 4, 2);

    // l3: fused upconv+blur 64->64, 64->128, parity-split (x sty4) -> Z3
    upblur_cl<<<dim3(16, 8, 16), blk, 0, stream>>>(Y2, ew3, dm3, l3_b, sty4, Z3, 64, 64, 64, 4);

    // l4: conv 64->32 @128 + fused final 1x1 (x styf/sqrt32) -> d_out
    conv3x3_cl<3><<<dim3(64, 1, 16), blk, 0, stream>>>(Z3, wp4, dm4, l4_b, styf, fin_w, obias, (float*)d_out, 64, 32, 128, 8, 2, 1);
}

// Round 10
// 322.034 us; speedup vs baseline: 1.1700x; 1.0621x over previous
//
#include <hip/hip_runtime.h>
#include <math.h>

#define SQRT2 1.41421356237309515f

typedef __bf16 bf16x8 __attribute__((ext_vector_type(8)));
typedef float f32x4 __attribute__((ext_vector_type(4)));
typedef unsigned short u16x4 __attribute__((ext_vector_type(4)));
typedef unsigned short u16x8 __attribute__((ext_vector_type(8)));

__device__ __forceinline__ unsigned short f2bf(float f) {
    unsigned u = __builtin_bit_cast(unsigned, f);
    u += 0x7fffu + ((u >> 16) & 1u);
    return (unsigned short)(u >> 16);
}

// ---------------- all styles in one kernel (shapes hardcoded)
__global__ __launch_bounds__(256) void style_all(
    const float* __restrict__ z,
    const float* __restrict__ mw0, const float* __restrict__ mb0,
    const float* __restrict__ mw1, const float* __restrict__ mb1,
    const float* __restrict__ mw2, const float* __restrict__ mb2,
    const float* __restrict__ mw3, const float* __restrict__ mb3,
    const float* __restrict__ mw4, const float* __restrict__ mb4,
    const float* __restrict__ mwf, const float* __restrict__ mbf,
    float* __restrict__ s0, float* __restrict__ s1, float* __restrict__ s2,
    float* __restrict__ s3, float* __restrict__ s4, float* __restrict__ sf) {
    int i = blockIdx.x * 256 + threadIdx.x;
    const float* mw; const float* mb; float* o; int Ci, idx; float mul = 1.f;
    if (i < 4096)       { mw = mw0; mb = mb0; o = s0; Ci = 256; idx = i; }
    else if (i < 6144)  { mw = mw1; mb = mb1; o = s1; Ci = 128; idx = i - 4096; }
    else if (i < 8192)  { mw = mw2; mb = mb2; o = s2; Ci = 128; idx = i - 6144; }
    else if (i < 9216)  { mw = mw3; mb = mb3; o = s3; Ci = 64;  idx = i - 8192; }
    else if (i < 10240) { mw = mw4; mb = mb4; o = s4; Ci = 64;  idx = i - 9216; }
    else if (i < 10752) { mw = mwf; mb = mbf; o = sf; Ci = 32;  idx = i - 10240;
                          mul = 0.1767766952966369f; }  // 1/sqrt(32)
    else return;
    int b = idx / Ci, ci = idx % Ci;
    const float* zp = z + b * 512;
    const float* wp = mw + ci * 512;
    float acc = 0.f;
#pragma unroll 8
    for (int k = 0; k < 512; ++k) acc += zp[k] * wp[k];
    o[idx] = (acc * 0.04419417382415922f + mb[ci]) * mul;
}

// ---------------- all demods: one wave per (b,co), layer decoded by wave id
__global__ __launch_bounds__(256) void demod_all(
    const float* __restrict__ w0, const float* __restrict__ w1,
    const float* __restrict__ w2, const float* __restrict__ w3,
    const float* __restrict__ w4,
    const float* __restrict__ s0, const float* __restrict__ s1,
    const float* __restrict__ s2, const float* __restrict__ s3,
    const float* __restrict__ s4,
    float* __restrict__ d0, float* __restrict__ d1, float* __restrict__ d2,
    float* __restrict__ d3, float* __restrict__ d4) {
    int wid = blockIdx.x * 4 + (threadIdx.x >> 6);
    int lane = threadIdx.x & 63;
    const float* w; const float* s; float* d; int Co, Ci, idx;
    if (wid < 2048)      { w = w0; s = s0; d = d0; Co = 128; Ci = 256; idx = wid; }
    else if (wid < 4096) { w = w1; s = s1; d = d1; Co = 128; Ci = 128; idx = wid - 2048; }
    else if (wid < 5120) { w = w2; s = s2; d = d2; Co = 64;  Ci = 128; idx = wid - 4096; }
    else if (wid < 6144) { w = w3; s = s3; d = d3; Co = 64;  Ci = 64;  idx = wid - 5120; }
    else if (wid < 6656) { w = w4; s = s4; d = d4; Co = 32;  Ci = 64;  idx = wid - 6144; }
    else return;
    int b = idx / Co, co = idx % Co;
    const float* wp = w + (size_t)co * Ci * 9;
    const float* sp = s + b * Ci;
    float acc = 0.f;
    for (int k = lane; k < Ci * 9; k += 64) {
        int ci = k / 9;
        float v = wp[k], sv = sp[ci];
        acc += v * v * sv * sv;
    }
    for (int off = 32; off > 0; off >>= 1) acc += __shfl_down(acc, off);
    if (lane == 0) d[b * Co + co] = rsqrtf(acc / (float)(Ci * 9) + 1e-8f);
}

// ---------------- pack helpers (CoG parameterized)
__device__ __forceinline__ void pack_cw_elem(
    const float* __restrict__ w, unsigned short* __restrict__ dst,
    int i, int Ci, int KT, int CoG, float sInv) {
    int cil = i & 31;
    int r = i >> 5;
    int col = r % CoG; r /= CoG;
    int t = r % 9; r /= 9;
    int c = r % KT, g = r / KT;
    int co = g * CoG + col, ci = c * 32 + cil;
    dst[i] = f2bf(w[((size_t)co * Ci + ci) * 9 + t] * sInv);
}
__device__ __forceinline__ void pack_fused_elem(
    const float* __restrict__ w, unsigned short* __restrict__ dst,
    int i, int Ci, int KT, int CoG, float sInv) {
    int cil = i & 31;
    int r = i >> 5;
    int col = r % CoG; r /= CoG;
    int t = r % 36; r /= 36;
    int c = r % KT, g = r / KT;
    int co = g * CoG + col, ci = c * 32 + cil;
    int p = t / 9, dd = (t % 9) / 3, ee = t % 3;
    int py = p >> 1, px = p & 1;
    const float k1[4] = {1.f, 3.f, 3.f, 1.f};
    const float* wq = w + ((size_t)co * Ci + ci) * 9;
    float acc = 0.f;
#pragma unroll
    for (int rr = 0; rr < 3; ++rr) {
        int ia = 2 * dd + rr - 1 - py;
        if (ia < 0 || ia > 3) continue;
#pragma unroll
        for (int ss = 0; ss < 3; ++ss) {
            int ib = 2 * ee + ss - 1 - px;
            if (ib < 0 || ib > 3) continue;
            acc += wq[rr * 3 + ss] * k1[ia] * k1[ib];
        }
    }
    dst[i] = f2bf(acc * sInv * (1.f / 16.f));
}

// ---------------- all weight packs in one kernel (segment ranges hardcoded)
__global__ __launch_bounds__(256) void pack_all(
    const float* __restrict__ l0w, const float* __restrict__ l1w,
    const float* __restrict__ l2w, const float* __restrict__ l3w,
    const float* __restrict__ l4w, unsigned short* __restrict__ base) {
    const float sInv1152 = 0.02946278254943948f;
    int i = blockIdx.x * 256 + threadIdx.x;
    if (i < 294912)       pack_cw_elem(l0w, base, i, 256, 8, 64, 1.f / 48.f);
    else if (i < 368640)  pack_cw_elem(l2w, base + 294912, i - 294912, 128, 4, 64, sInv1152);
    else if (i < 387072)  pack_cw_elem(l4w, base + 368640, i - 368640, 64, 2, 32, 1.f / 24.f);
    else if (i < 976896)  pack_fused_elem(l1w, base + 387072, i - 387072, 128, 4, 64, sInv1152);
    else if (i < 1124352) pack_fused_elem(l3w, base + 976896, i - 976896, 64, 2, 64, 1.f / 24.f);
}

// ---------------- composite + transpose to channel-last, x sty0 -> bf16
__global__ __launch_bounds__(256) void composite_cl_kernel(
    const float* __restrict__ fg, const float* __restrict__ mask,
    const float* __restrict__ bg, const float* __restrict__ sty0,
    unsigned short* __restrict__ out) {
    __shared__ unsigned short ldsT[32 * 264];
    int blk = blockIdx.x;
    int b = blk >> 5, y = blk & 31;
    int t = threadIdx.x;
    int x = t & 31, cr = t >> 5;
    const float* sb = sty0 + b * 256;
    float m = 1.f - mask[(b << 10) + (y << 5) + x];
    for (int k = 0; k < 32; ++k) {
        int ci = k * 8 + cr;
        size_t idx = ((size_t)(b * 256 + ci) << 10) + (y << 5) + x;
        float v = fg[idx] + m * bg[idx];
        ldsT[x * 264 + ci] = f2bf(v * sb[ci]);
    }
    __syncthreads();
    int xx = t >> 5, cu = t & 31;
#pragma unroll
    for (int ph = 0; ph < 4; ++ph) {
        int px = ph * 8 + xx;
        u16x8 v = *(const u16x8*)&ldsT[px * 264 + cu * 8];
        *(u16x8*)(out + (((size_t)(b * 32 + y) * 32 + px) << 8) + cu * 8) = v;
    }
}

// ---------------- MFMA 3x3 conv, channel-last, LDS-staged, MT co-tiles
// (each B-fragment read feeds MT MFMAs). r7-style interleaved reads, pad 36.
// OUTMODE 0: f32 split-K partial; 1: bf16 epilogue; 3: l4 + fused final 1x1.
template <int MT, int OUTMODE>
__global__ __launch_bounds__(256, 3) void conv3x3_cl(
    const unsigned short* __restrict__ X, const unsigned short* __restrict__ W,
    const float* __restrict__ demod, const float* __restrict__ bias,
    const float* __restrict__ nextsty, const float* __restrict__ finw,
    const float* __restrict__ ob, void* __restrict__ outv,
    int Ci, int Co, int S, int TPS, int KCH, int cogN) {
    __shared__ unsigned short ldsX[324 * 36];
    const int CoG = MT * 16;
    const int tid = threadIdx.x;
    const int b = blockIdx.z;
    const int ks = blockIdx.y / cogN, cog = blockIdx.y % cogN;
    const int tile = blockIdx.x;
    const int ty0 = (tile / TPS) * 16, tx0 = (tile % TPS) * 16;
    const int KT = Ci >> 5;
    const int wave = tid >> 6, lane = tid & 63, quad = lane >> 4, l16 = lane & 15;

    f32x4 acc[MT][4];
#pragma unroll
    for (int mt = 0; mt < MT; ++mt)
#pragma unroll
        for (int nt = 0; nt < 4; ++nt) acc[mt][nt] = (f32x4){0.f, 0.f, 0.f, 0.f};

    for (int cc = 0; cc < KCH; ++cc) {
        const int cg = ks * KCH + cc;
        const int ci0 = cg * 32;
        for (int u = tid; u < 1296; u += 256) {
            int sp = u >> 2, cq = u & 3;
            int y = sp / 18, xx = sp - y * 18;
            int gy = ty0 - 1 + y, gx = tx0 - 1 + xx;
            u16x8 pk = (u16x8){0, 0, 0, 0, 0, 0, 0, 0};
            if ((unsigned)gy < (unsigned)S && (unsigned)gx < (unsigned)S)
                pk = *(const u16x8*)(X + ((size_t)(b * S + gy) * S + gx) * Ci + ci0 + cq * 8);
            *(u16x8*)&ldsX[sp * 36 + cq * 8] = pk;
        }
        __syncthreads();
        const unsigned short* wt = W + (((size_t)cog * KT + cg) * 9) * (CoG * 32) + l16 * 32 + quad * 8;
#pragma unroll
        for (int t = 0; t < 9; ++t) {
            const int ty = t / 3, tx = t - ty * 3;
            bf16x8 af[MT];
#pragma unroll
            for (int mt = 0; mt < MT; ++mt)
                af[mt] = *(const bf16x8*)(const void*)(wt + t * (CoG * 32) + mt * 512);
#pragma unroll
            for (int nt = 0; nt < 4; ++nt) {
                int sp = (wave * 4 + nt + ty) * 18 + l16 + tx;
                bf16x8 bv = *(const bf16x8*)(const void*)&ldsX[sp * 36 + quad * 8];
#pragma unroll
                for (int mt = 0; mt < MT; ++mt)
                    acc[mt][nt] = __builtin_amdgcn_mfma_f32_16x16x32_bf16(af[mt], bv, acc[mt][nt], 0, 0, 0);
            }
        }
        __syncthreads();
    }
    const int col = tx0 + l16;
    if (OUTMODE == 0) {
        float* out = (float*)outv;
        const size_t PS = (size_t)16 * S * S * Co;
#pragma unroll
        for (int mt = 0; mt < MT; ++mt) {
            int co0 = cog * CoG + mt * 16 + quad * 4;
#pragma unroll
            for (int nt = 0; nt < 4; ++nt) {
                int row = ty0 + wave * 4 + nt;
                *(f32x4*)&out[ks * PS + ((size_t)(b * S + row) * S + col) * Co + co0] = acc[mt][nt];
            }
        }
    } else if (OUTMODE == 1) {
#pragma unroll
        for (int mt = 0; mt < MT; ++mt) {
            int co0 = cog * CoG + mt * 16 + quad * 4;
            f32x4 dm = *(const f32x4*)&demod[b * Co + co0];
            f32x4 bi = *(const f32x4*)&bias[co0];
            f32x4 ns = *(const f32x4*)&nextsty[b * Co + co0];
#pragma unroll
            for (int nt = 0; nt < 4; ++nt) {
                int row = ty0 + wave * 4 + nt;
                size_t base = ((size_t)(b * S + row) * S + col) * Co + co0;
                u16x4 st;
#pragma unroll
                for (int r = 0; r < 4; ++r) {
                    float v = acc[mt][nt][r] * dm[r] + bi[r];
                    v = (v > 0.f ? v : 0.2f * v) * SQRT2 * ns[r];
                    st[r] = f2bf(v);
                }
                *(u16x4*)((unsigned short*)outv + base) = st;
            }
        }
    } else {
        // l4 epilogue + fused final 1x1 (Co=32, MT=2, cog=0)
        f32x4 dm[MT], bi[MT], ns[MT];
        float fw[3][MT][4];
#pragma unroll
        for (int mt = 0; mt < MT; ++mt) {
            int c0 = mt * 16 + quad * 4;
            dm[mt] = *(const f32x4*)&demod[b * Co + c0];
            bi[mt] = *(const f32x4*)&bias[c0];
            ns[mt] = *(const f32x4*)&nextsty[b * Co + c0];
#pragma unroll
            for (int c = 0; c < 3; ++c)
#pragma unroll
                for (int r = 0; r < 4; ++r) fw[c][mt][r] = finw[c * 32 + c0 + r];
        }
        float* out = (float*)outv;
        float ob0 = ob[0], ob1 = ob[1], ob2 = ob[2];
#pragma unroll
        for (int nt = 0; nt < 4; ++nt) {
            int row = ty0 + wave * 4 + nt;
            float p0 = 0.f, p1 = 0.f, p2 = 0.f;
#pragma unroll
            for (int mt = 0; mt < MT; ++mt)
#pragma unroll
                for (int r = 0; r < 4; ++r) {
                    float v = acc[mt][nt][r] * dm[mt][r] + bi[mt][r];
                    v = (v > 0.f ? v : 0.2f * v) * SQRT2 * ns[mt][r];
                    p0 += v * fw[0][mt][r];
                    p1 += v * fw[1][mt][r];
                    p2 += v * fw[2][mt][r];
                }
            p0 += __shfl_xor(p0, 16); p0 += __shfl_xor(p0, 32);
            p1 += __shfl_xor(p1, 16); p1 += __shfl_xor(p1, 32);
            p2 += __shfl_xor(p2, 16); p2 += __shfl_xor(p2, 32);
            if (quad == 0) {
                size_t base = (((size_t)b * 3) << 14) + (row << 7) + col;
                out[base] = p0 + ob0;
                out[base + 16384] = p1 + ob1;
                out[base + 32768] = p2 + ob2;
            }
        }
    }
}

// ---------------- combine 4 split-K partials for l0 (+demod+bias+act+sty1) -> bf16
__global__ __launch_bounds__(256) void combine_l0_kernel(
    const float* __restrict__ P, const float* __restrict__ demod,
    const float* __restrict__ bias, const float* __restrict__ sty1,
    unsigned short* __restrict__ out) {
    int i = blockIdx.x * 256 + threadIdx.x;    // [b][y][x][128]
    const int PS = 1 << 21;
    int co = i & 127;
    int b = i >> 17;
    float v = (P[i] + P[i + PS]) + (P[i + 2 * PS] + P[i + 3 * PS]);
    v = v * demod[b * 128 + co] + bias[co];
    v = (v > 0.f ? v : 0.2f * v) * SQRT2 * sty1[b * 128 + co];
    out[i] = f2bf(v);
}

// ---------------- FUSED upconv+blur MFMA, channel-last, parity-per-block, MT co-tiles.
template <int MT>
__global__ __launch_bounds__(256, 3) void upblur_cl(
    const unsigned short* __restrict__ X, const unsigned short* __restrict__ EW,
    const float* __restrict__ demod, const float* __restrict__ bias,
    const float* __restrict__ nextsty, unsigned short* __restrict__ out,
    int Ci, int Co, int S, int TPS) {
    __shared__ unsigned short ldsX[324 * 36];
    const int CoG = MT * 16;
    const int tid = threadIdx.x;
    const int b = blockIdx.z;
    const int cog = blockIdx.y >> 2, p = blockIdx.y & 3;
    const int tile = blockIdx.x;
    const int ty0 = (tile / TPS) * 16, tx0 = (tile % TPS) * 16;
    const int KT = Ci >> 5;
    const int wave = tid >> 6, lane = tid & 63, quad = lane >> 4, l16 = lane & 15;

    f32x4 acc[MT][4];
#pragma unroll
    for (int mt = 0; mt < MT; ++mt)
#pragma unroll
        for (int nt = 0; nt < 4; ++nt) acc[mt][nt] = (f32x4){0.f, 0.f, 0.f, 0.f};

    for (int cc = 0; cc < KT; ++cc) {
        const int ci0 = cc * 32;
        for (int u = tid; u < 1296; u += 256) {
            int sp = u >> 2, cq = u & 3;
            int y = sp / 18, xx = sp - y * 18;
            int gy = ty0 - 1 + y, gx = tx0 - 1 + xx;
            u16x8 pk = (u16x8){0, 0, 0, 0, 0, 0, 0, 0};
            if ((unsigned)gy < (unsigned)S && (unsigned)gx < (unsigned)S)
                pk = *(const u16x8*)(X + ((size_t)(b * S + gy) * S + gx) * Ci + ci0 + cq * 8);
            *(u16x8*)&ldsX[sp * 36 + cq * 8] = pk;
        }
        __syncthreads();
        const unsigned short* wt = EW + (((size_t)cog * KT + cc) * 36 + p * 9) * (CoG * 32) + l16 * 32 + quad * 8;
#pragma unroll
        for (int t = 0; t < 9; ++t) {
            const int dd = t / 3, ee = t - dd * 3;
            bf16x8 af[MT];
#pragma unroll
            for (int mt = 0; mt < MT; ++mt)
                af[mt] = *(const bf16x8*)(const void*)(wt + t * (CoG * 32) + mt * 512);
#pragma unroll
            for (int nt = 0; nt < 4; ++nt) {
                int sp = (wave * 4 + nt + dd) * 18 + l16 + ee;
                bf16x8 bv = *(const bf16x8*)(const void*)&ldsX[sp * 36 + quad * 8];
#pragma unroll
                for (int mt = 0; mt < MT; ++mt)
                    acc[mt][nt] = __builtin_amdgcn_mfma_f32_16x16x32_bf16(af[mt], bv, acc[mt][nt], 0, 0, 0);
            }
        }
        __syncthreads();
    }
    const int S2 = 2 * S;
    const int py = p >> 1, px = p & 1;
    const int Xc = tx0 + l16, ox = 2 * Xc + px;
#pragma unroll
    for (int mt = 0; mt < MT; ++mt) {
        const int co0 = cog * CoG + mt * 16 + quad * 4;
        f32x4 dm = *(const f32x4*)&demod[b * Co + co0];
        f32x4 bi = *(const f32x4*)&bias[co0];
        f32x4 ns = *(const f32x4*)&nextsty[b * Co + co0];
#pragma unroll
        for (int nt = 0; nt < 4; ++nt) {
            int Y = ty0 + wave * 4 + nt, oy = 2 * Y + py;
            u16x4 st;
#pragma unroll
            for (int r = 0; r < 4; ++r) {
                float v = acc[mt][nt][r] * dm[r] + bi[r];
                v = (v > 0.f ? v : 0.2f * v) * SQRT2 * ns[r];
                st[r] = f2bf(v);
            }
            *(u16x4*)(out + ((size_t)(b * S2 + oy) * S2 + ox) * Co + co0) = st;
        }
    }
}

extern "C" void kernel_launch(void* const* d_in, const int* in_sizes, int n_in,
                              void* d_out, int out_size, void* d_ws, size_t ws_size,
                              hipStream_t stream) {
    const float* fg   = (const float*)d_in[0];
    const float* mask = (const float*)d_in[1];
    const float* bg   = (const float*)d_in[2];
    const float* z    = (const float*)d_in[3];
    const float* l0_w = (const float*)d_in[4];
    const float* l0_mw= (const float*)d_in[5];
    const float* l0_mb= (const float*)d_in[6];
    const float* l0_b = (const float*)d_in[7];
    const float* l1_w = (const float*)d_in[8];
    const float* l1_mw= (const float*)d_in[9];
    const float* l1_mb= (const float*)d_in[10];
    const float* l1_b = (const float*)d_in[11];
    const float* l2_w = (const float*)d_in[12];
    const float* l2_mw= (const float*)d_in[13];
    const float* l2_mb= (const float*)d_in[14];
    const float* l2_b = (const float*)d_in[15];
    const float* l3_w = (const float*)d_in[16];
    const float* l3_mw= (const float*)d_in[17];
    const float* l3_mb= (const float*)d_in[18];
    const float* l3_b = (const float*)d_in[19];
    const float* l4_w = (const float*)d_in[20];
    const float* l4_mw= (const float*)d_in[21];
    const float* l4_mb= (const float*)d_in[22];
    const float* l4_b = (const float*)d_in[23];
    const float* fin_w = (const float*)d_in[24];
    const float* fin_mw= (const float*)d_in[25];
    const float* fin_mb= (const float*)d_in[26];
    const float* obias = (const float*)d_in[27];

    float* wsf = (float*)d_ws;
    float* sty0 = wsf + 0;
    float* sty1 = wsf + 4096;
    float* sty2 = wsf + 6144;
    float* sty3 = wsf + 8192;
    float* sty4 = wsf + 9216;
    float* styf = wsf + 10240;   // pre-scaled by 1/sqrt(32)
    float* dm0  = wsf + 10752;
    float* dm1  = wsf + 12800;
    float* dm2  = wsf + 14848;
    float* dm3  = wsf + 15872;
    float* dm4  = wsf + 16896;
    // packed weights: one region, segment offsets match pack_all (CoG=64 except l4=32)
    unsigned short* wbase = (unsigned short*)(wsf + 17408);
    unsigned short* wp0 = wbase;            // 294912 sh
    unsigned short* wp2 = wbase + 294912;   // 73728 sh
    unsigned short* wp4 = wbase + 368640;   // 18432 sh
    unsigned short* ew1 = wbase + 387072;   // 589824 sh
    unsigned short* ew3 = wbase + 976896;   // 147456 sh, end 1124352 sh (=579584 fl end)
    // ---- channel-last activations (float offsets), lifetime-audited, disjoint:
    // X0 [600000, 2697152)     composite bf16 [b][32][32][256]; dead after l0
    // Pb [2697152, 11085760)   l0 split-K f32 [4][b][32][32][128]; dead after combine
    // Y0 [11085760, 12134336)  l0 out bf16 [b][32][32][128]; dead after upblur1
    // Z1 [12134336, 16328640)  l1 out bf16 [b][64][64][128]; dead after l2
    // Y2 = alias X0            l2 out bf16 [b][64][64][64]; dead after upblur3
    // Z3 [16328640, 24717248)  l3 out bf16 [b][128][128][64]; dead after l4
    unsigned short* X0  = (unsigned short*)(wsf + 600000);
    float* Pbuf = wsf + 2697152;
    unsigned short* Y0  = (unsigned short*)(wsf + 11085760);
    unsigned short* Z1  = (unsigned short*)(wsf + 12134336);
    unsigned short* Y2  = X0;
    unsigned short* Z3  = (unsigned short*)(wsf + 16328640);

    dim3 blk(256);

    // prep: 3 fused kernels
    style_all<<<42, blk, 0, stream>>>(z, l0_mw, l0_mb, l1_mw, l1_mb, l2_mw, l2_mb,
                                      l3_mw, l3_mb, l4_mw, l4_mb, fin_mw, fin_mb,
                                      sty0, sty1, sty2, sty3, sty4, styf);
    demod_all<<<1664, blk, 0, stream>>>(l0_w, l1_w, l2_w, l3_w, l4_w,
                                        sty0, sty1, sty2, sty3, sty4,
                                        dm0, dm1, dm2, dm3, dm4);
    pack_all<<<4392, blk, 0, stream>>>(l0_w, l1_w, l2_w, l3_w, l4_w, wbase);

    // composite (NCHW -> channel-last, x sty0) -> X0
    composite_cl_kernel<<<512, blk, 0, stream>>>(fg, mask, bg, sty0, X0);

    // l0: conv 256->128 @32, MT=4, split-K=4 x cog=2 -> Pbuf; combine (x sty1) -> Y0
    conv3x3_cl<4, 0><<<dim3(4, 8, 16), blk, 0, stream>>>(X0, wp0, nullptr, nullptr, nullptr, nullptr, nullptr, Pbuf, 256, 128, 32, 2, 2, 2);
    combine_l0_kernel<<<8192, blk, 0, stream>>>(Pbuf, dm0, l0_b, sty1, Y0);

    // l1: fused upconv+blur 128->128, 32->64, MT=4, parity-split (x sty2) -> Z1
    upblur_cl<4><<<dim3(4, 8, 16), blk, 0, stream>>>(Y0, ew1, dm1, l1_b, sty2, Z1, 128, 128, 32, 2);

    // l2: conv 128->64 @64, MT=4 (x sty3) -> Y2
    conv3x3_cl<4, 1><<<dim3(16, 1, 16), blk, 0, stream>>>(Z1, wp2, dm2, l2_b, sty3, nullptr, nullptr, Y2, 128, 64, 64, 4, 4, 1);

    // l3: fused upconv+blur 64->64, 64->128, MT=4, parity-split (x sty4) -> Z3
    upblur_cl<4><<<dim3(16, 4, 16), blk, 0, stream>>>(Y2, ew3, dm3, l3_b, sty4, Z3, 64, 64, 64, 4);

    // l4: conv 64->32 @128, MT=2 + fused final 1x1 (x styf/sqrt32) -> d_out
    conv3x3_cl<2, 3><<<dim3(64, 1, 16), blk, 0, stream>>>(Z3, wp4, dm4, l4_b, styf, fin_w, obias, (float*)d_out, 64, 32, 128, 8, 2, 1);
}